// Round 4
// baseline (1084.978 us; speedup 1.0000x reference)
//
#include <hip/hip_runtime.h>

#define D     128
#define NT    200000
#define NL    50000
#define ETA   1000000
#define EREV  1000000
#define ELL   500000
#define ELBL  500000

typedef __attribute__((ext_vector_type(8))) __bf16 bf16x8;
typedef __attribute__((ext_vector_type(4))) float f32x4;

#define LDS_STRIDE 136   // 272 B rows: 16B-aligned, 68 banks -> 2-way max aliasing (free)

// ---------------------------------------------------------------------------
// Weight prep: fp32 -> bf16, native [n][k] layout (= MFMA B-frag layout).
// Slot 0 = W_l_tl, 1 = W_r_tl, 2 = W_l_ll, 3 = W_r_tl + W_r_ll.
// bias_sum = b_tl + b_ll.
// ---------------------------------------------------------------------------
__global__ __launch_bounds__(256) void prep_weights(
    const float* __restrict__ Wl_tl, const float* __restrict__ Wr_tl,
    const float* __restrict__ Wl_ll, const float* __restrict__ Wr_ll,
    const float* __restrict__ b_tl, const float* __restrict__ b_ll,
    __bf16* __restrict__ Wb, float* __restrict__ bias_sum)
{
    int i = blockIdx.x * 256 + threadIdx.x;
    if (i < D * D) {
        Wb[i]             = (__bf16)Wl_tl[i];
        Wb[D * D + i]     = (__bf16)Wr_tl[i];
        Wb[2 * D * D + i] = (__bf16)Wl_ll[i];
        Wb[3 * D * D + i] = (__bf16)(Wr_tl[i] + Wr_ll[i]);
    }
    if (i < D) bias_sum[i] = b_tl[i] + b_ll[i];
}

// ---------------------------------------------------------------------------
// Degree count, all three edge lists in one launch.
// ---------------------------------------------------------------------------
__global__ __launch_bounds__(256) void count_all(
    const int* __restrict__ ta_dst, const int* __restrict__ ll_dst,
    const int* __restrict__ rev_dst,
    int* __restrict__ cntTa, int* __restrict__ cntLl, int* __restrict__ cntRev)
{
    int i = blockIdx.x * 256 + threadIdx.x;
    if (i < ETA) { atomicAdd(&cntTa[ta_dst[i]], 1); return; }
    int j = i - ETA;
    if (j < ELL) { atomicAdd(&cntLl[ll_dst[j]], 1); return; }
    int k = j - ELL;
    if (k < EREV) atomicAdd(&cntRev[rev_dst[k]], 1);
}

// ---------------------------------------------------------------------------
// Segment allocation without a scan: each wave prefix-sums 64 degrees and
// grabs a chunk with ONE atomicAdd (segment order across rows is irrelevant).
// cur[row] = segment start (becomes end after fill).
// ---------------------------------------------------------------------------
__global__ __launch_bounds__(256) void alloc_all(
    const int* __restrict__ cntTa, const int* __restrict__ cntLl,
    const int* __restrict__ cntRev,
    int* __restrict__ curTa, int* __restrict__ curLl, int* __restrict__ curRev,
    int* __restrict__ gcnt)
{
    const int BTA = (NL + 255) / 256;
    const int BLL = BTA + (NL + 255) / 256;
    int b = blockIdx.x;
    const int* cnt; int* cur; int* g; int n; int i0;
    if (b < BTA)      { cnt = cntTa;  cur = curTa;  g = gcnt + 0; n = NL; i0 = b * 256; }
    else if (b < BLL) { cnt = cntLl;  cur = curLl;  g = gcnt + 1; n = NL; i0 = (b - BTA) * 256; }
    else              { cnt = cntRev; cur = curRev; g = gcnt + 2; n = NT; i0 = (b - BLL) * 256; }
    int i = i0 + threadIdx.x;
    int lane = threadIdx.x & 63;
    int deg = (i < n) ? cnt[i] : 0;
    int incl = deg;
#pragma unroll
    for (int off = 1; off < 64; off <<= 1) {
        int v = __shfl_up(incl, off, 64);
        if (lane >= off) incl += v;
    }
    int excl = incl - deg;
    int total = __shfl(incl, 63, 64);
    int base = 0;
    if (lane == 63) base = atomicAdd(g, total);
    base = __shfl(base, 63, 64);
    if (i < n) cur[i] = base + excl;
}

// ---------------------------------------------------------------------------
// CSR fill, all three edge lists in one launch. remap applied to label srcs.
// ---------------------------------------------------------------------------
__global__ __launch_bounds__(256) void fill_all(
    const int* __restrict__ ta_src, const int* __restrict__ ta_dst,
    const int* __restrict__ ll_src, const int* __restrict__ ll_dst,
    const int* __restrict__ rev_src, const int* __restrict__ rev_dst,
    const int* __restrict__ remap,
    int* __restrict__ curTa, int* __restrict__ curLl, int* __restrict__ curRev,
    int* __restrict__ csrTa, int* __restrict__ csrLl, int* __restrict__ csrRev)
{
    int i = blockIdx.x * 256 + threadIdx.x;
    if (i < ETA) {
        int pos = atomicAdd(&curTa[ta_dst[i]], 1);
        csrTa[pos] = ta_src[i];
        return;
    }
    int j = i - ETA;
    if (j < ELL) {
        int pos = atomicAdd(&curLl[ll_dst[j]], 1);
        csrLl[pos] = remap[ll_src[j]];
        return;
    }
    int k = j - ELL;
    if (k < EREV) {
        int pos = atomicAdd(&curRev[rev_dst[k]], 1);
        csrRev[pos] = remap[rev_src[k]];
    }
}

// ---------------------------------------------------------------------------
// FUSED title side: aggregate meanRev into LDS (bf16), stage x_title into
// LDS, then MFMA: out = relu(meanRev @ Wl_tl^T + b_tl + x_title @ Wr_tl^T).
// Block = 32 rows x 128 cols; 4 waves. No mean array ever touches HBM.
// ---------------------------------------------------------------------------
__global__ __launch_bounds__(256) void title_fused(
    const float* __restrict__ xTitle, const float* __restrict__ labelEmbed,
    const int* __restrict__ csrRev, const int* __restrict__ cntRev,
    const int* __restrict__ curRev, const __bf16* __restrict__ Wb,
    const float* __restrict__ b_tl, float* __restrict__ outTitle)
{
    __shared__ __bf16 sM[32][LDS_STRIDE];
    __shared__ __bf16 sX[32][LDS_STRIDE];
    const int w = threadIdx.x >> 6, lane = threadIdx.x & 63;
    const int r0 = blockIdx.x * 32;

    // Phase 1: wave w aggregates rows w*8 .. w*8+7.
    for (int rr = 0; rr < 8; ++rr) {
        int r = w * 8 + rr;
        int row = r0 + r;
        int deg = cntRev[row];
        int end = curRev[row];
        int e = end - deg;
        float ax = 0.f, ay = 0.f;
        for (; e + 1 < end; e += 2) {
            int s0 = csrRev[e], s1 = csrRev[e + 1];
            float2 v0 = *reinterpret_cast<const float2*>(labelEmbed + (size_t)s0 * D + lane * 2);
            float2 v1 = *reinterpret_cast<const float2*>(labelEmbed + (size_t)s1 * D + lane * 2);
            ax += v0.x + v1.x; ay += v0.y + v1.y;
        }
        if (e < end) {
            int s0 = csrRev[e];
            float2 v0 = *reinterpret_cast<const float2*>(labelEmbed + (size_t)s0 * D + lane * 2);
            ax += v0.x; ay += v0.y;
        }
        float rc = 1.0f / fmaxf((float)deg, 1.0f);
        sM[r][lane * 2]     = (__bf16)(ax * rc);
        sM[r][lane * 2 + 1] = (__bf16)(ay * rc);
        float2 xv = *reinterpret_cast<const float2*>(xTitle + (size_t)row * D + lane * 2);
        sX[r][lane * 2]     = (__bf16)xv.x;
        sX[r][lane * 2 + 1] = (__bf16)xv.y;
    }
    __syncthreads();

    // Phase 2: MFMA. Wave w: mtile=w&1 (16 rows), n-half=(w>>1) (64 cols).
    const int m15 = lane & 15, q = lane >> 4;
    const int mtile = w & 1, n0 = (w >> 1) * 64;
    const int ar = mtile * 16 + m15;

    bf16x8 aM[4], aX[4];
#pragma unroll
    for (int kc = 0; kc < 4; ++kc) {
        aM[kc] = *reinterpret_cast<const bf16x8*>(&sM[ar][kc * 32 + q * 8]);
        aX[kc] = *reinterpret_cast<const bf16x8*>(&sX[ar][kc * 32 + q * 8]);
    }
    f32x4 acc[4] = {{0.f,0.f,0.f,0.f},{0.f,0.f,0.f,0.f},{0.f,0.f,0.f,0.f},{0.f,0.f,0.f,0.f}};
    const __bf16* W0 = Wb;            // W_l_tl [n][k]
    const __bf16* W1 = Wb + D * D;    // W_r_tl [n][k]
#pragma unroll
    for (int kc = 0; kc < 4; ++kc) {
#pragma unroll
        for (int nt = 0; nt < 4; ++nt) {
            int n = n0 + nt * 16 + m15;
            bf16x8 b0 = *reinterpret_cast<const bf16x8*>(W0 + n * D + kc * 32 + q * 8);
            bf16x8 b1 = *reinterpret_cast<const bf16x8*>(W1 + n * D + kc * 32 + q * 8);
            acc[nt] = __builtin_amdgcn_mfma_f32_16x16x32_bf16(aM[kc], b0, acc[nt], 0, 0, 0);
            acc[nt] = __builtin_amdgcn_mfma_f32_16x16x32_bf16(aX[kc], b1, acc[nt], 0, 0, 0);
        }
    }
#pragma unroll
    for (int nt = 0; nt < 4; ++nt) {
        float bias = b_tl[n0 + nt * 16 + m15];
#pragma unroll
        for (int rg = 0; rg < 4; ++rg) {
            int row = r0 + mtile * 16 + q * 4 + rg;
            outTitle[(size_t)row * D + n0 + nt * 16 + m15] = fmaxf(acc[nt][rg] + bias, 0.0f);
        }
    }
}

// ---------------------------------------------------------------------------
// FUSED label side: aggregate meanTa (from x_title) and meanLl (from
// label_embed) into LDS, stage x_label, then MFMA with 3 A-matrices:
// out = relu(meanTa@Wl_tl^T + meanLl@Wl_ll^T + x_label@(Wr_tl+Wr_ll)^T + bias_sum).
// ---------------------------------------------------------------------------
__global__ __launch_bounds__(256) void label_fused(
    const float* __restrict__ xTitle, const float* __restrict__ labelEmbed,
    const int* __restrict__ labelNodeId,
    const int* __restrict__ csrTa, const int* __restrict__ cntTa, const int* __restrict__ curTa,
    const int* __restrict__ csrLl, const int* __restrict__ cntLl, const int* __restrict__ curLl,
    const __bf16* __restrict__ Wb, const float* __restrict__ bias_sum,
    float* __restrict__ outLabel)
{
    __shared__ __bf16 sT[32][LDS_STRIDE];
    __shared__ __bf16 sL[32][LDS_STRIDE];
    __shared__ __bf16 sE[32][LDS_STRIDE];
    const int w = threadIdx.x >> 6, lane = threadIdx.x & 63;
    const int r0 = blockIdx.x * 32;

    for (int rr = 0; rr < 8; ++rr) {
        int r = w * 8 + rr;
        int row = r0 + r;
        if (row >= NL) {
            sT[r][lane * 2] = (__bf16)0.f; sT[r][lane * 2 + 1] = (__bf16)0.f;
            sL[r][lane * 2] = (__bf16)0.f; sL[r][lane * 2 + 1] = (__bf16)0.f;
            sE[r][lane * 2] = (__bf16)0.f; sE[r][lane * 2 + 1] = (__bf16)0.f;
            continue;
        }
        // ta segment: sources are title nodes.
        {
            int deg = cntTa[row];
            int end = curTa[row];
            int e = end - deg;
            float ax = 0.f, ay = 0.f;
            for (; e + 1 < end; e += 2) {
                int s0 = csrTa[e], s1 = csrTa[e + 1];
                float2 v0 = *reinterpret_cast<const float2*>(xTitle + (size_t)s0 * D + lane * 2);
                float2 v1 = *reinterpret_cast<const float2*>(xTitle + (size_t)s1 * D + lane * 2);
                ax += v0.x + v1.x; ay += v0.y + v1.y;
            }
            if (e < end) {
                int s0 = csrTa[e];
                float2 v0 = *reinterpret_cast<const float2*>(xTitle + (size_t)s0 * D + lane * 2);
                ax += v0.x; ay += v0.y;
            }
            float rc = 1.0f / fmaxf((float)deg, 1.0f);
            sT[r][lane * 2]     = (__bf16)(ax * rc);
            sT[r][lane * 2 + 1] = (__bf16)(ay * rc);
        }
        // ll segment: sources are label nodes (already remapped in fill).
        {
            int deg = cntLl[row];
            int end = curLl[row];
            int e = end - deg;
            float ax = 0.f, ay = 0.f;
            for (; e + 1 < end; e += 2) {
                int s0 = csrLl[e], s1 = csrLl[e + 1];
                float2 v0 = *reinterpret_cast<const float2*>(labelEmbed + (size_t)s0 * D + lane * 2);
                float2 v1 = *reinterpret_cast<const float2*>(labelEmbed + (size_t)s1 * D + lane * 2);
                ax += v0.x + v1.x; ay += v0.y + v1.y;
            }
            if (e < end) {
                int s0 = csrLl[e];
                float2 v0 = *reinterpret_cast<const float2*>(labelEmbed + (size_t)s0 * D + lane * 2);
                ax += v0.x; ay += v0.y;
            }
            float rc = 1.0f / fmaxf((float)deg, 1.0f);
            sL[r][lane * 2]     = (__bf16)(ax * rc);
            sL[r][lane * 2 + 1] = (__bf16)(ay * rc);
        }
        // x_label row.
        {
            int xr = labelNodeId[row];
            float2 xv = *reinterpret_cast<const float2*>(labelEmbed + (size_t)xr * D + lane * 2);
            sE[r][lane * 2]     = (__bf16)xv.x;
            sE[r][lane * 2 + 1] = (__bf16)xv.y;
        }
    }
    __syncthreads();

    const int m15 = lane & 15, q = lane >> 4;
    const int mtile = w & 1, n0 = (w >> 1) * 64;
    const int ar = mtile * 16 + m15;

    bf16x8 aT[4], aL[4], aE[4];
#pragma unroll
    for (int kc = 0; kc < 4; ++kc) {
        aT[kc] = *reinterpret_cast<const bf16x8*>(&sT[ar][kc * 32 + q * 8]);
        aL[kc] = *reinterpret_cast<const bf16x8*>(&sL[ar][kc * 32 + q * 8]);
        aE[kc] = *reinterpret_cast<const bf16x8*>(&sE[ar][kc * 32 + q * 8]);
    }
    f32x4 acc[4] = {{0.f,0.f,0.f,0.f},{0.f,0.f,0.f,0.f},{0.f,0.f,0.f,0.f},{0.f,0.f,0.f,0.f}};
    const __bf16* W0 = Wb;                // W_l_tl
    const __bf16* W2 = Wb + 2 * D * D;    // W_l_ll
    const __bf16* W3 = Wb + 3 * D * D;    // W_r_tl + W_r_ll
#pragma unroll
    for (int kc = 0; kc < 4; ++kc) {
#pragma unroll
        for (int nt = 0; nt < 4; ++nt) {
            int n = n0 + nt * 16 + m15;
            bf16x8 b0 = *reinterpret_cast<const bf16x8*>(W0 + n * D + kc * 32 + q * 8);
            bf16x8 b2 = *reinterpret_cast<const bf16x8*>(W2 + n * D + kc * 32 + q * 8);
            bf16x8 b3 = *reinterpret_cast<const bf16x8*>(W3 + n * D + kc * 32 + q * 8);
            acc[nt] = __builtin_amdgcn_mfma_f32_16x16x32_bf16(aT[kc], b0, acc[nt], 0, 0, 0);
            acc[nt] = __builtin_amdgcn_mfma_f32_16x16x32_bf16(aL[kc], b2, acc[nt], 0, 0, 0);
            acc[nt] = __builtin_amdgcn_mfma_f32_16x16x32_bf16(aE[kc], b3, acc[nt], 0, 0, 0);
        }
    }
#pragma unroll
    for (int nt = 0; nt < 4; ++nt) {
        float bias = bias_sum[n0 + nt * 16 + m15];
#pragma unroll
        for (int rg = 0; rg < 4; ++rg) {
            int row = r0 + mtile * 16 + q * 4 + rg;
            if (row < NL)
                outLabel[(size_t)row * D + n0 + nt * 16 + m15] = fmaxf(acc[nt][rg] + bias, 0.0f);
        }
    }
}

// ---------------------------------------------------------------------------
// Supervision-edge dot products: 32 lanes per edge, float4 per lane.
// ---------------------------------------------------------------------------
__global__ __launch_bounds__(256) void pred_kernel(
    const float* __restrict__ outTitle, const float* __restrict__ outLabel,
    const int* __restrict__ elSrc, const int* __restrict__ elDst,
    float* __restrict__ pred, int E)
{
    int idx = blockIdx.x * 256 + threadIdx.x;
    int e = idx >> 5;
    if (e >= E) return;
    int l = idx & 31;
    int s = elSrc[e];
    int d = elDst[e];
    float4 a = *reinterpret_cast<const float4*>(outTitle + (size_t)s * D + l * 4);
    float4 b = *reinterpret_cast<const float4*>(outLabel + (size_t)d * D + l * 4);
    float v = a.x * b.x + a.y * b.y + a.z * b.z + a.w * b.w;
#pragma unroll
    for (int off = 16; off > 0; off >>= 1) v += __shfl_down(v, off, 32);
    if (l == 0) pred[e] = v;
}

// ---------------------------------------------------------------------------
extern "C" void kernel_launch(void* const* d_in, const int* in_sizes, int n_in,
                              void* d_out, int out_size, void* d_ws, size_t ws_size,
                              hipStream_t stream)
{
    const float* x_title       = (const float*)d_in[0];
    const float* label_embed   = (const float*)d_in[1];
    const float* W_l_tl        = (const float*)d_in[2];
    const float* b_l_tl        = (const float*)d_in[3];
    const float* W_r_tl        = (const float*)d_in[4];
    const float* W_l_ll        = (const float*)d_in[5];
    const float* b_l_ll        = (const float*)d_in[6];
    const float* W_r_ll        = (const float*)d_in[7];
    const int*   label_node_id = (const int*)d_in[8];
    const int*   ta_src        = (const int*)d_in[9];
    const int*   ta_dst        = (const int*)d_in[10];
    const int*   rev_src       = (const int*)d_in[11];
    const int*   rev_dst       = (const int*)d_in[12];
    const int*   ll_src        = (const int*)d_in[13];
    const int*   ll_dst        = (const int*)d_in[14];
    const int*   el_src        = (const int*)d_in[15];
    const int*   el_dst        = (const int*)d_in[16];

    float* out       = (float*)d_out;
    float* pred      = out;                        // [ELBL]
    float* out_title = out + ELBL;                 // [NT*D]
    float* out_label = out_title + (size_t)NT * D; // [NL*D]

    // Workspace layout.
    __bf16* Wb       = (__bf16*)d_ws;                      // 4*D*D bf16
    float*  bias_sum = (float*)(Wb + 4 * D * D);           // D floats
    int*    cntTa    = (int*)(bias_sum + D);               // NL
    int*    cntLl    = cntTa + NL;                         // NL
    int*    cntRev   = cntLl + NL;                         // NT
    int*    gcnt     = cntRev + NT;                        // 3
    int*    curTa    = gcnt + 3;                           // NL
    int*    curLl    = curTa + NL;                         // NL
    int*    curRev   = curLl + NL;                         // NT
    int*    csrTa    = curRev + NT;                        // ETA
    int*    csrLl    = csrTa + ETA;                        // ELL
    int*    csrRev   = csrLl + ELL;                        // EREV

    // Zero degree counters + global cursors (contiguous block).
    hipMemsetAsync(cntTa, 0, (size_t)(NL + NL + NT + 3) * sizeof(int), stream);

    prep_weights<<<(D * D + 255) / 256, 256, 0, stream>>>(
        W_l_tl, W_r_tl, W_l_ll, W_r_ll, b_l_tl, b_l_ll, Wb, bias_sum);

    const int ETOT = ETA + ELL + EREV;
    count_all<<<(ETOT + 255) / 256, 256, 0, stream>>>(
        ta_dst, ll_dst, rev_dst, cntTa, cntLl, cntRev);

    const int ABLK = (NL + 255) / 256 + (NL + 255) / 256 + (NT + 255) / 256;
    alloc_all<<<ABLK, 256, 0, stream>>>(
        cntTa, cntLl, cntRev, curTa, curLl, curRev, gcnt);

    fill_all<<<(ETOT + 255) / 256, 256, 0, stream>>>(
        ta_src, ta_dst, ll_src, ll_dst, rev_src, rev_dst, label_node_id,
        curTa, curLl, curRev, csrTa, csrLl, csrRev);

    // Fused aggregate + GEMM + bias + ReLU (means never touch HBM).
    label_fused<<<(NL + 31) / 32, 256, 0, stream>>>(
        x_title, label_embed, label_node_id,
        csrTa, cntTa, curTa, csrLl, cntLl, curLl,
        Wb, bias_sum, out_label);
    title_fused<<<NT / 32, 256, 0, stream>>>(
        x_title, label_embed, csrRev, cntRev, curRev, Wb, b_l_tl, out_title);

    // Supervision-edge dot products.
    pred_kernel<<<(ELBL * 32) / 256, 256, 0, stream>>>(
        out_title, out_label, el_src, el_dst, pred, ELBL);
}